// Round 1
// baseline (559.133 us; speedup 1.0000x reference)
//
#include <hip/hip_runtime.h>
#include <hip/hip_bf16.h>
#include <hip/hip_fp16.h>

typedef __attribute__((ext_vector_type(8))) short short8;
typedef __attribute__((ext_vector_type(4))) float f32x4;
typedef unsigned short u16;

// ---------- helpers ----------
__device__ __forceinline__ u16 f2bf(float f) {
  union { float f; unsigned u; } v; v.f = f;
  unsigned r = v.u + 0x7fffu + ((v.u >> 16) & 1u);
  return (u16)(r >> 16);
}
__device__ __forceinline__ float bf2f(u16 u) {
  union { unsigned u; float f; } v; v.u = ((unsigned)u) << 16;
  return v.f;
}
__device__ __forceinline__ void gload16(const void* g, void* l) {
  __builtin_amdgcn_global_load_lds(
      (const __attribute__((address_space(1))) unsigned*)g,
      (__attribute__((address_space(3))) unsigned*)l, 16, 0, 0);
}

// ---------- LayerNorm: fp32 [rows,1024] -> bf16 ----------
__global__ __launch_bounds__(256)
void ln_bf16(const float* __restrict__ X, const float* __restrict__ gamma,
             const float* __restrict__ beta, u16* __restrict__ Y) {
  const int row = blockIdx.x;
  const int tid = threadIdx.x;
  const long base = (long)row * 1024 + tid * 4;
  float4 x = *(const float4*)(X + base);
  float s = x.x + x.y + x.z + x.w;
  float q = x.x * x.x + x.y * x.y + x.z * x.z + x.w * x.w;
#pragma unroll
  for (int o = 32; o > 0; o >>= 1) {
    s += __shfl_xor(s, o);
    q += __shfl_xor(q, o);
  }
  __shared__ float rs[4], rq[4];
  if ((tid & 63) == 0) { rs[tid >> 6] = s; rq[tid >> 6] = q; }
  __syncthreads();
  s = rs[0] + rs[1] + rs[2] + rs[3];
  q = rq[0] + rq[1] + rq[2] + rq[3];
  float mu = s * (1.f / 1024.f);
  float var = q * (1.f / 1024.f) - mu * mu;
  float rstd = rsqrtf(var + 1e-5f);
  float4 g = *(const float4*)(gamma + tid * 4);
  float4 b = *(const float4*)(beta + tid * 4);
  ushort4 o4;
  o4.x = f2bf((x.x - mu) * rstd * g.x + b.x);
  o4.y = f2bf((x.y - mu) * rstd * g.y + b.y);
  o4.z = f2bf((x.z - mu) * rstd * g.z + b.z);
  o4.w = f2bf((x.w - mu) * rstd * g.w + b.w);
  *(ushort4*)(Y + base) = o4;
}

// ---------- fp32 -> bf16 convert (weights) ----------
__global__ __launch_bounds__(256)
void cvt_bf16(const float* __restrict__ in, u16* __restrict__ out, int n4) {
  int i = blockIdx.x * blockDim.x + threadIdx.x;
  if (i < n4) {
    float4 x = ((const float4*)in)[i];
    ushort4 o;
    o.x = f2bf(x.x); o.y = f2bf(x.y); o.z = f2bf(x.z); o.w = f2bf(x.w);
    ((ushort4*)out)[i] = o;
  }
}

// ---------- row softmax in place: fp16 logits -> bf16 probs, row len 2048 ----------
__global__ __launch_bounds__(256)
void softmax_inplace(u16* __restrict__ LP) {
  const int tid = threadIdx.x;
  const long base = (long)blockIdx.x * 2048 + tid * 8;
  const __half* hp = (const __half*)LP + base;
  short8 raw = *(const short8*)hp;
  float x[8];
#pragma unroll
  for (int i = 0; i < 8; ++i) x[i] = __half2float(((const __half*)&raw)[i]);
  float m = x[0];
#pragma unroll
  for (int i = 1; i < 8; ++i) m = fmaxf(m, x[i]);
#pragma unroll
  for (int o = 32; o > 0; o >>= 1) m = fmaxf(m, __shfl_xor(m, o));
  __shared__ float red[8];
  if ((tid & 63) == 0) red[tid >> 6] = m;
  __syncthreads();
  m = fmaxf(fmaxf(red[0], red[1]), fmaxf(red[2], red[3]));
  float e[8];
  float s = 0.f;
#pragma unroll
  for (int i = 0; i < 8; ++i) { e[i] = __expf(x[i] - m); s += e[i]; }
#pragma unroll
  for (int o = 32; o > 0; o >>= 1) s += __shfl_xor(s, o);
  if ((tid & 63) == 0) red[4 + (tid >> 6)] = s;
  __syncthreads();
  s = red[4] + red[5] + red[6] + red[7];
  float inv = 1.f / s;
  short8 out;
#pragma unroll
  for (int i = 0; i < 8; ++i) ((u16*)&out)[i] = f2bf(e[i] * inv);
  *(short8*)((__half*)LP + base) = out;
}

// ---------- GEMM (A [M,K] bf16, B [N,K] bf16 i.e. B^T layout), 128x128 tile ----------
// MODE 0: bf16 out = acc + bias[col]
// MODE 1: fp16 out = acc * scale
// MODE 2: bf16 transposed store V_t[b][col][row] = acc + bias[col]  (M spans batches)
// MODE 3: bf16 out = acc + R1 + R2 (residual)
// MODE 4: fp32 out = acc + bias[col]
template <int MODE>
__global__ __launch_bounds__(256)
void gemm_bt(const u16* __restrict__ A, const u16* __restrict__ B,
             const float* __restrict__ bias, void* __restrict__ Cp,
             const u16* __restrict__ R1, const u16* __restrict__ R2,
             int M, int N, int K, long sA, long sB, long sC, float scale) {
  __shared__ u16 as[128][32];
  __shared__ u16 bs[128][32];
  const int bz = blockIdx.z;
  const u16* Ab = A + (long)bz * sA;
  const u16* Bb = B + (long)bz * sB;
  const long cb = (long)bz * sC;

  const int tid = threadIdx.x;
  const int lane = tid & 63;
  const int wave = tid >> 6;
  const int wr = (wave >> 1) * 64;
  const int wc = (wave & 1) * 64;
  const long rowBase = (long)blockIdx.y * 128;
  const long colBase = (long)blockIdx.x * 128;

  const int sr = tid >> 2;
  const int sc = (tid & 3) * 8;
  const int fr = lane & 15;
  const int koff = (lane >> 4) * 8;

  f32x4 acc[4][4] = {};

  for (int kk = 0; kk < K; kk += 32) {
    __syncthreads();
    gload16(Ab + (rowBase + sr) * (long)K + kk + sc, &as[sr][sc]);
    gload16(Ab + (rowBase + sr + 64) * (long)K + kk + sc, &as[sr + 64][sc]);
    gload16(Bb + (colBase + sr) * (long)K + kk + sc, &bs[sr][sc]);
    gload16(Bb + (colBase + sr + 64) * (long)K + kk + sc, &bs[sr + 64][sc]);
    __syncthreads();
    short8 af[4], bf[4];
#pragma unroll
    for (int m = 0; m < 4; ++m)
      af[m] = *(const short8*)&as[wr + m * 16 + fr][koff];
#pragma unroll
    for (int n = 0; n < 4; ++n)
      bf[n] = *(const short8*)&bs[wc + n * 16 + fr][koff];
#pragma unroll
    for (int m = 0; m < 4; ++m)
#pragma unroll
      for (int n = 0; n < 4; ++n)
        acc[m][n] = __builtin_amdgcn_mfma_f32_16x16x32_bf16(af[m], bf[n], acc[m][n], 0, 0, 0);
  }

#pragma unroll
  for (int m = 0; m < 4; ++m) {
#pragma unroll
    for (int n = 0; n < 4; ++n) {
#pragma unroll
      for (int j = 0; j < 4; ++j) {
        long r = rowBase + wr + m * 16 + (lane >> 4) * 4 + j;
        long c = colBase + wc + n * 16 + fr;
        float v = acc[m][n][j];
        if (MODE == 0) {
          ((u16*)Cp)[cb + r * N + c] = f2bf(v + bias[c]);
        } else if (MODE == 1) {
          ((__half*)Cp)[cb + r * N + c] = __float2half(v * scale);
        } else if (MODE == 2) {
          long b2 = r >> 11;
          long i = r & 2047;
          ((u16*)Cp)[b2 * (1024L * 2048) + c * 2048 + i] = f2bf(v + bias[c]);
        } else if (MODE == 3) {
          long idx = cb + r * N + c;
          ((u16*)Cp)[idx] = f2bf(v + bf2f(R1[idx]) + bf2f(R2[idx]));
        } else {
          ((float*)Cp)[cb + r * N + c] = v + bias[c];
        }
      }
    }
  }
}

// ---------- launcher ----------
extern "C" void kernel_launch(void* const* d_in, const int* in_sizes, int n_in,
                              void* d_out, int out_size, void* d_ws, size_t ws_size,
                              hipStream_t stream) {
  const float* img  = (const float*)d_in[0];
  const float* refp = (const float*)d_in[1];
  const float* pose = (const float*)d_in[2];
  const float* gam  = (const float*)d_in[3];
  const float* bet  = (const float*)d_in[4];
  const float* Wq = (const float*)d_in[5];
  const float* bq = (const float*)d_in[6];
  const float* Wk = (const float*)d_in[7];
  const float* bk = (const float*)d_in[8];
  const float* Wv = (const float*)d_in[9];
  const float* bv = (const float*)d_in[10];
  const float* Wo = (const float*)d_in[11];
  const float* bo = (const float*)d_in[12];

  char* ws = (char*)d_ws;
  const size_t MB = 1u << 20;
  u16* Wq_b = (u16*)(ws + 0 * MB);
  u16* Wk_b = (u16*)(ws + 2 * MB);
  u16* Wv_b = (u16*)(ws + 4 * MB);
  u16* Wo_b = (u16*)(ws + 6 * MB);
  u16* bufA = (u16*)(ws + 8 * MB);    // ref_n, later K-proj
  u16* bufB = (u16*)(ws + 40 * MB);   // pose_n
  u16* bufC = (u16*)(ws + 72 * MB);   // img_n
  u16* bufD = (u16*)(ws + 104 * MB);  // Q, later X
  u16* bufE = (u16*)(ws + 136 * MB);  // V^T
  u16* bufL = (u16*)(ws + 168 * MB);  // logits fp16 -> probs bf16 (64 MB), ends at 232 MB

  // weights to bf16
  cvt_bf16<<<1024, 256, 0, stream>>>(Wq, Wq_b, 1024 * 1024 / 4);
  cvt_bf16<<<1024, 256, 0, stream>>>(Wk, Wk_b, 1024 * 1024 / 4);
  cvt_bf16<<<1024, 256, 0, stream>>>(Wv, Wv_b, 1024 * 1024 / 4);
  cvt_bf16<<<768, 256, 0, stream>>>(Wo, Wo_b, 768 * 1024 / 4);

  // layernorms (16384 rows each)
  ln_bf16<<<16384, 256, 0, stream>>>(refp, gam, bet, bufA);
  ln_bf16<<<16384, 256, 0, stream>>>(pose, gam, bet, bufB);
  ln_bf16<<<16384, 256, 0, stream>>>(img, gam, bet, bufC);

  // Q = ref_n @ Wq^T + bq
  gemm_bt<0><<<dim3(8, 128, 1), 256, 0, stream>>>(bufA, Wq_b, bq, bufD, nullptr, nullptr,
                                                  16384, 1024, 1024, 0, 0, 0, 1.f);
  // V^T = (img_n @ Wv^T + bv)^T  (per batch [1024][2048])
  gemm_bt<2><<<dim3(8, 128, 1), 256, 0, stream>>>(bufC, Wv_b, bv, bufE, nullptr, nullptr,
                                                  16384, 1024, 1024, 0, 0, 0, 1.f);
  // K = pose_n @ Wk^T + bk   (overwrites bufA; ref_n dead)
  gemm_bt<0><<<dim3(8, 128, 1), 256, 0, stream>>>(bufB, Wk_b, bk, bufA, nullptr, nullptr,
                                                  16384, 1024, 1024, 0, 0, 0, 1.f);
  // logits = Q @ K^T * 1/32  (fp16, per batch 2048x2048)
  gemm_bt<1><<<dim3(16, 16, 8), 256, 0, stream>>>(bufD, bufA, nullptr, bufL, nullptr, nullptr,
                                                  2048, 2048, 1024,
                                                  2048L * 1024, 2048L * 1024, 2048L * 2048,
                                                  0.03125f);
  // softmax rows -> bf16 probs in place
  softmax_inplace<<<16384, 256, 0, stream>>>(bufL);
  // X = P @ V + pose_n + img_n  (bf16, overwrites bufD; Q dead)
  gemm_bt<3><<<dim3(8, 16, 8), 256, 0, stream>>>(bufL, bufE, nullptr, bufD, bufB, bufC,
                                                 2048, 1024, 2048,
                                                 2048L * 2048, 1024L * 2048, 2048L * 1024, 1.f);
  // out = X @ Wo^T + bo  (fp32)
  gemm_bt<4><<<dim3(6, 128, 1), 256, 0, stream>>>(bufD, Wo_b, bo, d_out, nullptr, nullptr,
                                                  16384, 768, 1024, 0, 0, 0, 1.f);
}

// Round 2
// 400.589 us; speedup vs baseline: 1.3958x; 1.3958x over previous
//
#include <hip/hip_runtime.h>
#include <hip/hip_bf16.h>
#include <hip/hip_fp16.h>

typedef __attribute__((ext_vector_type(8))) short short8;
typedef __attribute__((ext_vector_type(4))) float f32x4;
typedef unsigned short u16;

// ---------- helpers ----------
__device__ __forceinline__ u16 f2bf(float f) {
  union { float f; unsigned u; } v; v.f = f;
  unsigned r = v.u + 0x7fffu + ((v.u >> 16) & 1u);
  return (u16)(r >> 16);
}
__device__ __forceinline__ float bf2f(u16 u) {
  union { unsigned u; float f; } v; v.u = ((unsigned)u) << 16;
  return v.f;
}
__device__ __forceinline__ void gload16(const void* g, void* l) {
  __builtin_amdgcn_global_load_lds(
      (const __attribute__((address_space(1))) unsigned*)g,
      (__attribute__((address_space(3))) unsigned*)l, 16, 0, 0);
}

#define FENCE asm volatile("" ::: "memory")

// ---------- LayerNorm: fp32 [rows,1024] -> bf16 ----------
__global__ __launch_bounds__(256)
void ln_bf16(const float* __restrict__ X, const float* __restrict__ gamma,
             const float* __restrict__ beta, u16* __restrict__ Y) {
  const int row = blockIdx.x;
  const int tid = threadIdx.x;
  const long base = (long)row * 1024 + tid * 4;
  float4 x = *(const float4*)(X + base);
  float s = x.x + x.y + x.z + x.w;
  float q = x.x * x.x + x.y * x.y + x.z * x.z + x.w * x.w;
#pragma unroll
  for (int o = 32; o > 0; o >>= 1) {
    s += __shfl_xor(s, o);
    q += __shfl_xor(q, o);
  }
  __shared__ float rs[4], rq[4];
  if ((tid & 63) == 0) { rs[tid >> 6] = s; rq[tid >> 6] = q; }
  __syncthreads();
  s = rs[0] + rs[1] + rs[2] + rs[3];
  q = rq[0] + rq[1] + rq[2] + rq[3];
  float mu = s * (1.f / 1024.f);
  float var = q * (1.f / 1024.f) - mu * mu;
  float rstd = rsqrtf(var + 1e-5f);
  float4 g = *(const float4*)(gamma + tid * 4);
  float4 b = *(const float4*)(beta + tid * 4);
  ushort4 o4;
  o4.x = f2bf((x.x - mu) * rstd * g.x + b.x);
  o4.y = f2bf((x.y - mu) * rstd * g.y + b.y);
  o4.z = f2bf((x.z - mu) * rstd * g.z + b.z);
  o4.w = f2bf((x.w - mu) * rstd * g.w + b.w);
  *(ushort4*)(Y + base) = o4;
}

// ---------- fp32 -> bf16 convert (weights) ----------
__global__ __launch_bounds__(256)
void cvt_bf16(const float* __restrict__ in, u16* __restrict__ out, int n4) {
  int i = blockIdx.x * blockDim.x + threadIdx.x;
  if (i < n4) {
    float4 x = ((const float4*)in)[i];
    ushort4 o;
    o.x = f2bf(x.x); o.y = f2bf(x.y); o.z = f2bf(x.z); o.w = f2bf(x.w);
    ((ushort4*)out)[i] = o;
  }
}

// ---------- row softmax in place: fp16 logits -> bf16 probs, row len 2048 ----------
__global__ __launch_bounds__(256)
void softmax_inplace(u16* __restrict__ LP) {
  const int tid = threadIdx.x;
  const long base = (long)blockIdx.x * 2048 + tid * 8;
  const __half* hp = (const __half*)LP + base;
  short8 raw = *(const short8*)hp;
  float x[8];
#pragma unroll
  for (int i = 0; i < 8; ++i) x[i] = __half2float(((const __half*)&raw)[i]);
  float m = x[0];
#pragma unroll
  for (int i = 1; i < 8; ++i) m = fmaxf(m, x[i]);
#pragma unroll
  for (int o = 32; o > 0; o >>= 1) m = fmaxf(m, __shfl_xor(m, o));
  __shared__ float red[8];
  if ((tid & 63) == 0) red[tid >> 6] = m;
  __syncthreads();
  m = fmaxf(fmaxf(red[0], red[1]), fmaxf(red[2], red[3]));
  float e[8];
  float s = 0.f;
#pragma unroll
  for (int i = 0; i < 8; ++i) { e[i] = __expf(x[i] - m); s += e[i]; }
#pragma unroll
  for (int o = 32; o > 0; o >>= 1) s += __shfl_xor(s, o);
  if ((tid & 63) == 0) red[4 + (tid >> 6)] = s;
  __syncthreads();
  s = red[4] + red[5] + red[6] + red[7];
  float inv = 1.f / s;
  short8 out;
#pragma unroll
  for (int i = 0; i < 8; ++i) ((u16*)&out)[i] = f2bf(e[i] * inv);
  *(short8*)((__half*)LP + base) = out;
}

// ---------- 256x256 8-phase GEMM (A [M,K] bf16, B [N,K] bf16), BK=64 ----------
// 512 threads = 8 waves (2 Mx4 N), per-wave C = 128x64, acc 8x4 frags.
// LDS 128 KiB: [buf0|buf1] x [A 256x64 (2 halves of 128 rows) | B 256x64].
// Swizzle: 16B chunk c within a 128B row stored at slot c ^ (row&7); staged via
// pre-swizzled global source (global_load_lds writes linearly), read with same XOR.
// MODE 0: bf16 out = acc + bias[col]
// MODE 1: fp16 out = acc * scale
// MODE 2: bf16 transposed store V_t[b][col][row] = acc + bias[col]
// MODE 3: bf16 out = acc + R1 + R2
// MODE 4: fp32 out = acc + bias[col]
template <int MODE>
__global__ __launch_bounds__(512, 2)
void gemm256(const u16* __restrict__ A, const u16* __restrict__ B,
             const float* __restrict__ bias, void* __restrict__ Cp,
             const u16* __restrict__ R1, const u16* __restrict__ R2,
             int M, int N, int K, long sA, long sB, long sC, float scale) {
  extern __shared__ char lds[];
  const int bz = blockIdx.z;
  const u16* Ab = A + (long)bz * sA;
  const u16* Bb = B + (long)bz * sB;
  const long cb = (long)bz * sC;

  const int tid = threadIdx.x;
  const int lane = tid & 63;
  const int wid = tid >> 6;
  const int wr = wid >> 2;   // 0..1
  const int wc = wid & 3;    // 0..3
  const long rowBase = (long)blockIdx.y * 256;
  const long colBase = (long)blockIdx.x * 256;
  const int fr = lane & 15;
  const int fk = lane >> 4;  // 0..3
  const int nt = K >> 6;

  // stage half-tile h (128 rows x 64 cols) of A (bOff=0) or B (bOff=32768)
  auto stage = [&](const u16* __restrict__ gb, long rcBase, int t, int h, int bOff) {
    char* base = lds + (t & 1) * 65536 + bOff + h * 16384;
    const long kk = (long)t << 6;
#pragma unroll
    for (int i = 0; i < 2; ++i) {
      const int o = i * 8192 + tid * 16;   // linear byte in half-tile
      const int row = o >> 7;              // 0..127
      const int cs = (o >> 4) & 7;         // 16B chunk slot
      const long gr = rcBase + h * 128 + row;
      const long gk = kk + (long)((cs ^ (row & 7)) << 3);
      gload16(gb + gr * (long)K + gk, base + o);
    }
  };

  auto ldA = [&](int t, int m, int ks) -> short8 {
    const int row = wr * 128 + m * 16 + fr;               // 0..255
    const int ch = (ks * 4 + fk) ^ (row & 7);
    return *(const short8*)(lds + (t & 1) * 65536 + row * 128 + ch * 16);
  };
  auto ldB = [&](int t, int n, int ks) -> short8 {
    const int row = wc * 64 + n * 16 + fr;                // 0..255
    const int ch = (ks * 4 + fk) ^ (row & 7);
    return *(const short8*)(lds + (t & 1) * 65536 + 32768 + row * 128 + ch * 16);
  };

  f32x4 acc[8][4] = {};
  short8 bq[4][2];

  // prologue: tile0 all 4 halves, tile1 A0,B0,B1 (A1(1) staged at t=0 p0)
  stage(Ab, rowBase, 0, 0, 0);
  stage(Ab, rowBase, 0, 1, 0);
  stage(Bb, colBase, 0, 0, 32768);
  stage(Bb, colBase, 0, 1, 32768);
  if (nt > 1) {
    stage(Ab, rowBase, 1, 0, 0);
    stage(Bb, colBase, 1, 0, 32768);
    stage(Bb, colBase, 1, 1, 32768);
    asm volatile("s_waitcnt vmcnt(6)" ::: "memory");
  } else {
    asm volatile("s_waitcnt vmcnt(0)" ::: "memory");
  }
  FENCE; __builtin_amdgcn_s_barrier(); FENCE;

#define DO_PHASE(M0, STAGE, VMW)                                                                         \
  do {                                                                                                   \
    short8 a00 = ldA(t, (M0), 0), a01 = ldA(t, (M0), 1);                                                 \
    short8 a10 = ldA(t, (M0) + 1, 0), a11 = ldA(t, (M0) + 1, 1);                                         \
    STAGE;                                                                                               \
    VMW;                                                                                                 \
    FENCE; __builtin_amdgcn_s_barrier(); FENCE;                                                          \
    __builtin_amdgcn_s_setprio(1);                                                                       \
    _Pragma("unroll")                                                                                    \
    for (int n = 0; n < 4; ++n) {                                                                        \
      acc[(M0)][n] = __builtin_amdgcn_mfma_f32_16x16x32_bf16(a00, bq[n][0], acc[(M0)][n], 0, 0, 0);      \
      acc[(M0)][n] = __builtin_amdgcn_mfma_f32_16x16x32_bf16(a01, bq[n][1], acc[(M0)][n], 0, 0, 0);      \
      acc[(M0) + 1][n] = __builtin_amdgcn_mfma_f32_16x16x32_bf16(a10, bq[n][0], acc[(M0) + 1][n], 0, 0, 0); \
      acc[(M0) + 1][n] = __builtin_amdgcn_mfma_f32_16x16x32_bf16(a11, bq[n][1], acc[(M0) + 1][n], 0, 0, 0); \
    }                                                                                                    \
    __builtin_amdgcn_s_setprio(0);                                                                       \
    FENCE; __builtin_amdgcn_s_barrier(); FENCE;                                                          \
  } while (0)

  for (int t = 0; t < nt; ++t) {
#pragma unroll
    for (int n = 0; n < 4; ++n) {
      bq[n][0] = ldB(t, n, 0);
      bq[n][1] = ldB(t, n, 1);
    }
    DO_PHASE(0, { if (t + 1 < nt) stage(Ab, rowBase, t + 1, 1, 0); }, {});
    DO_PHASE(2, { if (t + 2 < nt) stage(Bb, colBase, t + 2, 0, 32768); }, {});
    DO_PHASE(4, { if (t + 2 < nt) stage(Bb, colBase, t + 2, 1, 32768); }, {});
    DO_PHASE(6, { if (t + 2 < nt) stage(Ab, rowBase, t + 2, 0, 0); },
             {
               if (t + 2 < nt) { asm volatile("s_waitcnt vmcnt(6)" ::: "memory"); }
               else            { asm volatile("s_waitcnt vmcnt(0)" ::: "memory"); }
             });
  }
#undef DO_PHASE

  // epilogue
#pragma unroll
  for (int m = 0; m < 8; ++m) {
#pragma unroll
    for (int n = 0; n < 4; ++n) {
#pragma unroll
      for (int j = 0; j < 4; ++j) {
        long r = rowBase + wr * 128 + m * 16 + fk * 4 + j;
        long c = colBase + wc * 64 + n * 16 + fr;
        float v = acc[m][n][j];
        if (MODE == 0) {
          ((u16*)Cp)[cb + r * N + c] = f2bf(v + bias[c]);
        } else if (MODE == 1) {
          ((__half*)Cp)[cb + r * N + c] = __float2half(v * scale);
        } else if (MODE == 2) {
          long b2 = r >> 11;
          long i = r & 2047;
          ((u16*)Cp)[b2 * (1024L * 2048) + c * 2048 + i] = f2bf(v + bias[c]);
        } else if (MODE == 3) {
          long idx = cb + r * N + c;
          ((u16*)Cp)[idx] = f2bf(v + bf2f(R1[idx]) + bf2f(R2[idx]));
        } else {
          ((float*)Cp)[cb + r * N + c] = v + bias[c];
        }
      }
    }
  }
}

// ---------- launcher ----------
extern "C" void kernel_launch(void* const* d_in, const int* in_sizes, int n_in,
                              void* d_out, int out_size, void* d_ws, size_t ws_size,
                              hipStream_t stream) {
  const float* img  = (const float*)d_in[0];
  const float* refp = (const float*)d_in[1];
  const float* pose = (const float*)d_in[2];
  const float* gam  = (const float*)d_in[3];
  const float* bet  = (const float*)d_in[4];
  const float* Wq = (const float*)d_in[5];
  const float* bq = (const float*)d_in[6];
  const float* Wk = (const float*)d_in[7];
  const float* bk = (const float*)d_in[8];
  const float* Wv = (const float*)d_in[9];
  const float* bv = (const float*)d_in[10];
  const float* Wo = (const float*)d_in[11];
  const float* bo = (const float*)d_in[12];

  char* ws = (char*)d_ws;
  const size_t MB = 1u << 20;
  u16* Wq_b = (u16*)(ws + 0 * MB);
  u16* Wk_b = (u16*)(ws + 2 * MB);
  u16* Wv_b = (u16*)(ws + 4 * MB);
  u16* Wo_b = (u16*)(ws + 6 * MB);
  u16* bufA = (u16*)(ws + 8 * MB);    // ref_n, later K-proj
  u16* bufB = (u16*)(ws + 40 * MB);   // pose_n
  u16* bufC = (u16*)(ws + 72 * MB);   // img_n
  u16* bufD = (u16*)(ws + 104 * MB);  // Q, later X
  u16* bufE = (u16*)(ws + 136 * MB);  // V^T
  u16* bufL = (u16*)(ws + 168 * MB);  // logits fp16 -> probs bf16 (64 MB)

  const int LDSB = 131072;
  hipFuncSetAttribute((const void*)gemm256<0>, hipFuncAttributeMaxDynamicSharedMemorySize, LDSB);
  hipFuncSetAttribute((const void*)gemm256<1>, hipFuncAttributeMaxDynamicSharedMemorySize, LDSB);
  hipFuncSetAttribute((const void*)gemm256<2>, hipFuncAttributeMaxDynamicSharedMemorySize, LDSB);
  hipFuncSetAttribute((const void*)gemm256<3>, hipFuncAttributeMaxDynamicSharedMemorySize, LDSB);
  hipFuncSetAttribute((const void*)gemm256<4>, hipFuncAttributeMaxDynamicSharedMemorySize, LDSB);

  // weights to bf16
  cvt_bf16<<<1024, 256, 0, stream>>>(Wq, Wq_b, 1024 * 1024 / 4);
  cvt_bf16<<<1024, 256, 0, stream>>>(Wk, Wk_b, 1024 * 1024 / 4);
  cvt_bf16<<<1024, 256, 0, stream>>>(Wv, Wv_b, 1024 * 1024 / 4);
  cvt_bf16<<<768, 256, 0, stream>>>(Wo, Wo_b, 768 * 1024 / 4);

  // layernorms (16384 rows each)
  ln_bf16<<<16384, 256, 0, stream>>>(refp, gam, bet, bufA);
  ln_bf16<<<16384, 256, 0, stream>>>(pose, gam, bet, bufB);
  ln_bf16<<<16384, 256, 0, stream>>>(img, gam, bet, bufC);

  // Q = ref_n @ Wq^T + bq
  gemm256<0><<<dim3(4, 64, 1), 512, LDSB, stream>>>(bufA, Wq_b, bq, bufD, nullptr, nullptr,
                                                    16384, 1024, 1024, 0, 0, 0, 1.f);
  // V^T = (img_n @ Wv^T + bv)^T  (per batch [1024][2048])
  gemm256<2><<<dim3(4, 64, 1), 512, LDSB, stream>>>(bufC, Wv_b, bv, bufE, nullptr, nullptr,
                                                    16384, 1024, 1024, 0, 0, 0, 1.f);
  // K = pose_n @ Wk^T + bk   (overwrites bufA; ref_n dead)
  gemm256<0><<<dim3(4, 64, 1), 512, LDSB, stream>>>(bufB, Wk_b, bk, bufA, nullptr, nullptr,
                                                    16384, 1024, 1024, 0, 0, 0, 1.f);
  // logits = Q @ K^T * 1/32  (fp16, per batch 2048x2048)
  gemm256<1><<<dim3(8, 8, 8), 512, LDSB, stream>>>(bufD, bufA, nullptr, bufL, nullptr, nullptr,
                                                   2048, 2048, 1024,
                                                   2048L * 1024, 2048L * 1024, 2048L * 2048,
                                                   0.03125f);
  // softmax rows -> bf16 probs in place
  softmax_inplace<<<16384, 256, 0, stream>>>(bufL);
  // X = P @ V + pose_n + img_n  (bf16, overwrites bufD; Q dead)
  gemm256<3><<<dim3(4, 8, 8), 512, LDSB, stream>>>(bufL, bufE, nullptr, bufD, bufB, bufC,
                                                   2048, 1024, 2048,
                                                   2048L * 2048, 1024L * 2048, 2048L * 1024, 1.f);
  // out = X @ Wo^T + bo  (fp32)
  gemm256<4><<<dim3(3, 64, 1), 512, LDSB, stream>>>(bufD, Wo_b, bo, d_out, nullptr, nullptr,
                                                    16384, 768, 1024, 0, 0, 0, 1.f);
}